// Round 7
// baseline (468.774 us; speedup 1.0000x reference)
//
#include <hip/hip_runtime.h>
#include <hip/hip_bf16.h>

#define HID 64
#define WPAD 68
#define SCAN_B 128
#define SCAN_T 256
#define NXCD 8

// bf16 rows: 64 bf16 = 128 B. Lane f in [0,8) owns uint4 chunk f = feats [8f, 8f+8).
static __device__ __forceinline__ float bflo(unsigned u) { return __uint_as_float(u << 16); }
static __device__ __forceinline__ float bfhi(unsigned u) {
    return __uint_as_float(u & 0xFFFF0000u);
}
static __device__ __forceinline__ unsigned packbf(float a, float b) {
    __hip_bfloat16 ha = __float2bfloat16(a), hb = __float2bfloat16(b);
    unsigned short ua = *reinterpret_cast<unsigned short*>(&ha);
    unsigned short ub = *reinterpret_cast<unsigned short*>(&hb);
    return (unsigned)ua | ((unsigned)ub << 16);
}

// ---------------- CSR build ----------------

__global__ __launch_bounds__(256) void count_kernel(const int* __restrict__ ei, int E,
                                                    int* __restrict__ cnt) {
    int stride = gridDim.x * blockDim.x;
    for (int e = blockIdx.x * blockDim.x + threadIdx.x; e < E; e += stride)
        atomicAdd(&cnt[ei[E + e]], 1);
}

__global__ __launch_bounds__(256) void fill_part(const int* __restrict__ ei, int E, int N,
                                                 const float* __restrict__ dinv,
                                                 int* __restrict__ cursor,
                                                 int2* __restrict__ csr) {
    int xcd = blockIdx.x & (NXCD - 1);
    int sl = blockIdx.x >> 3;
    int nsl = gridDim.x >> 3;
    int nlo = (int)((long long)N * xcd / NXCD);
    int nhi = (int)((long long)N * (xcd + 1) / NXCD);
    int stride = nsl * blockDim.x;
    for (int e = sl * blockDim.x + threadIdx.x; e < E; e += stride) {
        int d = ei[E + e];
        if (d >= nlo && d < nhi) {
            int s = ei[e];
            int pos = atomicAdd(&cursor[d], 1);
            csr[pos] = make_int2(s, __float_as_int(dinv[s]));
        }
    }
}

__global__ void dinv_kernel(const int* __restrict__ cnt, float* __restrict__ dinv,
                            const int* __restrict__ batch, int* __restrict__ pcnt, int N) {
    int stride = gridDim.x * blockDim.x;
    for (int n = blockIdx.x * blockDim.x + threadIdx.x; n < N; n += stride) {
        dinv[n] = rsqrtf((float)(cnt[n] + 1));  // deg includes self-loop
        atomicAdd(&pcnt[batch[n]], 1);
    }
}

__global__ void scan_sum(const int* __restrict__ cnt, int N, int* __restrict__ bsum) {
    int b = blockIdx.x;
    int chunk = (N + SCAN_B - 1) / SCAN_B;
    int lo = b * chunk, hi = min(lo + chunk, N);
    int s = 0;
    for (int i = lo + threadIdx.x; i < hi; i += SCAN_T) s += cnt[i];
    for (int off = 32; off; off >>= 1) s += __shfl_xor(s, off);
    __shared__ int red[SCAN_T / 64];
    int wave = threadIdx.x >> 6, lane = threadIdx.x & 63;
    if (lane == 0) red[wave] = s;
    __syncthreads();
    if (threadIdx.x == 0) {
        int t = 0;
        for (int w = 0; w < SCAN_T / 64; w++) t += red[w];
        bsum[b] = t;
    }
}

__global__ void scan_bsum(const int* __restrict__ bsum, int* __restrict__ bofs) {
    if (blockIdx.x == 0 && threadIdx.x == 0) {
        int r = 0;
        for (int b = 0; b < SCAN_B; b++) { bofs[b] = r; r += bsum[b]; }
    }
}

__global__ void scan_chunk(const int* __restrict__ cnt, int N, const int* __restrict__ bofs,
                           int* __restrict__ row_start, int* __restrict__ cursor) {
    int b = blockIdx.x;
    int chunk = (N + SCAN_B - 1) / SCAN_B;
    int lo = b * chunk, hi = min(lo + chunk, N);
    __shared__ int s[SCAN_T];
    __shared__ int carry;
    if (threadIdx.x == 0) carry = bofs[b];
    __syncthreads();
    for (int base = lo; base < hi; base += SCAN_T) {
        int i = base + threadIdx.x;
        int v = (i < hi) ? cnt[i] : 0;
        s[threadIdx.x] = v;
        __syncthreads();
        for (int off = 1; off < SCAN_T; off <<= 1) {
            int t = (threadIdx.x >= off) ? s[threadIdx.x - off] : 0;
            __syncthreads();
            s[threadIdx.x] += t;
            __syncthreads();
        }
        int incl = s[threadIdx.x];
        int c = carry;
        if (i < hi) {
            int ex = c + incl - v;
            row_start[i] = ex;
            cursor[i] = ex;
        }
        __syncthreads();
        if (threadIdx.x == SCAN_T - 1) carry = c + incl;
        __syncthreads();
    }
}

// ---------------- LDS weight staging (padded) ----------------

__device__ __forceinline__ void stageW(const float* __restrict__ W, float* __restrict__ sW) {
    for (int i = threadIdx.x; i < HID * HID; i += 256) {
        int r = i >> 6, c = i & 63;
        sW[r * WPAD + c] = W[i];
    }
    __syncthreads();
}

// ---------------- quarter-split matmul for layer1 (16-lane x 4-feat layout) ----------------
__device__ __forceinline__ float4 qmatmul(float4 h4, const float* __restrict__ sW, int q, int sl) {
    float4 z4 = make_float4(0.f, 0.f, 0.f, 0.f);
#pragma unroll
    for (int t = 0; t < 16; t++) {
        int k = (q << 4) + t;
        int srclane = 20 * q + (t >> 2);
        float comp = ((t & 3) == 0) ? h4.x : ((t & 3) == 1) ? h4.y : ((t & 3) == 2) ? h4.z : h4.w;
        float hk = __shfl(comp, srclane);
        const float4 w4 = *reinterpret_cast<const float4*>(&sW[k * WPAD + sl * 4]);
        z4.x += hk * w4.x; z4.y += hk * w4.y; z4.z += hk * w4.z; z4.w += hk * w4.w;
    }
#pragma unroll
    for (int off = 16; off <= 32; off <<= 1) {
        z4.x += __shfl_xor(z4.x, off);
        z4.y += __shfl_xor(z4.y, off);
        z4.z += __shfl_xor(z4.z, off);
        z4.w += __shfl_xor(z4.w, off);
    }
    return z4;
}

// ---------------- Layer 1: scalar propagate + fused (relu(p*W1+b1)) @ W2 -> bf16 ----------

__global__ __launch_bounds__(256) void layer1_kernel(
    const float* __restrict__ x, const int2* __restrict__ csr,
    const int* __restrict__ row_start, const int* __restrict__ cnt, const float* __restrict__ dinv,
    const float* __restrict__ W1, const float* __restrict__ b1, const float* __restrict__ W2,
    uint2* __restrict__ zb, int N) {
    __shared__ float sW2[HID * WPAD];
    stageW(W2, sW2);
    int lane = threadIdx.x & 63;
    int q = lane >> 4, sl = lane & 15;
    int n = blockIdx.x * 4 + (threadIdx.x >> 6);
    if (n >= N) return;
    int start = row_start[n], deg = cnt[n];
    float acc = 0.f;
    for (int i = start + lane; i < start + deg; i += 64) {
        int2 ew = csr[i];
        acc += __int_as_float(ew.y) * x[ew.x];
    }
#pragma unroll
    for (int off = 32; off; off >>= 1) acc += __shfl_xor(acc, off);
    float dn = dinv[n];
    float p = dn * (acc + dn * x[n]);  // wave-uniform
    float h = fmaxf(p * W1[lane] + b1[lane], 0.f);  // one feature per lane
    float4 h4;
    h4.x = __shfl(h, (sl << 2) + 0);
    h4.y = __shfl(h, (sl << 2) + 1);
    h4.z = __shfl(h, (sl << 2) + 2);
    h4.w = __shfl(h, (sl << 2) + 3);
    float4 z4 = qmatmul(h4, sW2, q, sl);
    if (q == 0)
        zb[(size_t)n * 16 + sl] = make_uint2(packbf(z4.x, z4.y), packbf(z4.z, z4.w));
}

// ---------------- 64-wide propagate over bf16 rows (layers 2,3) ----------------
// Lane = (grp 0..7, f 0..7). 8 edges per gather instruction (uint4/lane, 1 line/row).
// Edge metadata staged in LDS (broadcast ds_read, no bpermute in hot loop; dead
// slots pre-resolved to (self, w=0)).
// FUSE: out = relu(P(z)+bias) @ W -> bf16   (layer 2)
// POOL: segmented LDS reduce + one fp32 atomic run per distinct graph (layer 3 + pool)

template <bool FUSE, bool POOL>
__global__ __launch_bounds__(256) void p64_kernel(
    const uint4* __restrict__ zb, const int2* __restrict__ csr,
    const int* __restrict__ row_start, const int* __restrict__ cnt, const float* __restrict__ dinv,
    const float* __restrict__ bias, const float* __restrict__ W,
    uint4* __restrict__ outb, float* __restrict__ outp, const int* __restrict__ batch, int N) {
    __shared__ float sW[FUSE ? HID * WPAD : 1];
    __shared__ int2 ebuf[4][64];
    __shared__ float pbuf[POOL ? 4 : 1][POOL ? HID : 1];
    __shared__ int pg[4];
    if (FUSE) stageW(W, sW);
    int lane = threadIdx.x & 63;
    int wid = threadIdx.x >> 6;
    int grp = lane >> 3, f = lane & 7;
    int n = blockIdx.x * 4 + wid;
    bool valid = n < N;
    int nc = valid ? n : 0;
    int start = row_start[nc];
    int deg = valid ? cnt[nc] : 0;
    float dn = dinv[nc];

    float acc[8];
#pragma unroll
    for (int i = 0; i < 8; i++) acc[i] = 0.f;

    for (int base = 0; base < deg; base += 64) {
        int m = deg - base; if (m > 64) m = 64;
        int2 ew = (lane < m) ? csr[start + base + lane] : make_int2(nc, 0);
        ebuf[wid][lane] = ew;  // wave-local; compiler orders via lgkmcnt
        int kmax = (m + 7) >> 3;
        for (int kb = 0; kb < kmax; kb += 4) {
#pragma unroll
            for (int u = 0; u < 4; u++) {
                int k = kb + u;
                bool act = k < kmax;
                int2 e = ebuf[wid][(act ? k : 0) * 8 + grp];  // broadcast within group
                float ww = act ? __int_as_float(e.y) : 0.f;
                uint4 r = zb[(size_t)e.x * 8 + f];  // 8 lanes -> one 128B row
                acc[0] += ww * bflo(r.x); acc[1] += ww * bfhi(r.x);
                acc[2] += ww * bflo(r.y); acc[3] += ww * bfhi(r.y);
                acc[4] += ww * bflo(r.z); acc[5] += ww * bfhi(r.z);
                acc[6] += ww * bflo(r.w); acc[7] += ww * bfhi(r.w);
            }
        }
    }
    // reduce across the 8 groups (lanes sharing f)
#pragma unroll
    for (int i = 0; i < 8; i++) {
        acc[i] += __shfl_xor(acc[i], 8);
        acc[i] += __shfl_xor(acc[i], 16);
        acc[i] += __shfl_xor(acc[i], 32);
    }
    // self-loop + bias
    {
        uint4 su = zb[(size_t)nc * 8 + f];
        float sv[8] = {bflo(su.x), bfhi(su.x), bflo(su.y), bfhi(su.y),
                       bflo(su.z), bfhi(su.z), bflo(su.w), bfhi(su.w)};
        const float4 ba = *reinterpret_cast<const float4*>(&bias[(f << 3)]);
        const float4 bb = *reinterpret_cast<const float4*>(&bias[(f << 3) + 4]);
        acc[0] = dn * (acc[0] + dn * sv[0]) + ba.x;
        acc[1] = dn * (acc[1] + dn * sv[1]) + ba.y;
        acc[2] = dn * (acc[2] + dn * sv[2]) + ba.z;
        acc[3] = dn * (acc[3] + dn * sv[3]) + ba.w;
        acc[4] = dn * (acc[4] + dn * sv[4]) + bb.x;
        acc[5] = dn * (acc[5] + dn * sv[5]) + bb.y;
        acc[6] = dn * (acc[6] + dn * sv[6]) + bb.z;
        acc[7] = dn * (acc[7] + dn * sv[7]) + bb.w;
    }

    if (FUSE) {
        float h[8], ht[8], z[8];
#pragma unroll
        for (int i = 0; i < 8; i++) h[i] = fmaxf(acc[i], 0.f);
        // transpose shuffle: lane (grp,f) fetches h-chunk 'grp' from lane (f*8+grp)
        int srcl = (f << 3) | grp;
#pragma unroll
        for (int i = 0; i < 8; i++) ht[i] = __shfl(h[i], srcl);
#pragma unroll
        for (int i = 0; i < 8; i++) z[i] = 0.f;
#pragma unroll
        for (int i = 0; i < 8; i++) {
            int k = (grp << 3) + i;
            const float4 wa = *reinterpret_cast<const float4*>(&sW[k * WPAD + (f << 3)]);
            const float4 wb = *reinterpret_cast<const float4*>(&sW[k * WPAD + (f << 3) + 4]);
            z[0] += ht[i] * wa.x; z[1] += ht[i] * wa.y;
            z[2] += ht[i] * wa.z; z[3] += ht[i] * wa.w;
            z[4] += ht[i] * wb.x; z[5] += ht[i] * wb.y;
            z[6] += ht[i] * wb.z; z[7] += ht[i] * wb.w;
        }
#pragma unroll
        for (int i = 0; i < 8; i++) {
            z[i] += __shfl_xor(z[i], 8);
            z[i] += __shfl_xor(z[i], 16);
            z[i] += __shfl_xor(z[i], 32);
        }
        if (grp == 0 && valid)
            outb[(size_t)n * 8 + f] = make_uint4(packbf(z[0], z[1]), packbf(z[2], z[3]),
                                                 packbf(z[4], z[5]), packbf(z[6], z[7]));
    } else if (POOL) {
        if (grp == 0) {
            *reinterpret_cast<float4*>(&pbuf[wid][f << 3]) =
                make_float4(acc[0], acc[1], acc[2], acc[3]);
            *reinterpret_cast<float4*>(&pbuf[wid][(f << 3) + 4]) =
                make_float4(acc[4], acc[5], acc[6], acc[7]);
            if (lane == 0) pg[wid] = valid ? batch[n] : -1;
        }
        __syncthreads();
        if (wid == 0) {
            int j = lane;
            float v = 0.f;
            int gp = -1;
#pragma unroll
            for (int w = 0; w < 4; w++) {
                int gw = pg[w];  // wave-uniform
                if (gw < 0) continue;
                if (gw == gp) {
                    v += pbuf[w][j];
                } else {
                    if (gp >= 0) atomicAdd(&outp[(size_t)gp * HID + j], v);
                    v = pbuf[w][j];
                    gp = gw;
                }
            }
            if (gp >= 0) atomicAdd(&outp[(size_t)gp * HID + j], v);
        }
    }
}

// ---------------- head ----------------

__global__ void head_kernel(const float* __restrict__ psum, const int* __restrict__ pcnt,
                            const float* __restrict__ dist, const float* __restrict__ sw,
                            const float* __restrict__ Wl, const float* __restrict__ bl,
                            const float* __restrict__ Wl1, const float* __restrict__ bl1,
                            const float* __restrict__ Wl2, const float* __restrict__ bl2,
                            float* __restrict__ out, int G) {
    int g = blockIdx.x * blockDim.x + threadIdx.x;
    if (g >= G) return;
    float invc = 1.f / fmaxf((float)pcnt[g], 1.f);
    float a[5];
#pragma unroll
    for (int k = 0; k < 5; k++) a[k] = bl[k];
    for (int j = 0; j < HID; j++) {
        float p = psum[(size_t)g * HID + j] * invc;
#pragma unroll
        for (int k = 0; k < 5; k++) a[k] += p * Wl[j * 5 + k];
    }
    float g7[7];
#pragma unroll
    for (int k = 0; k < 5; k++) g7[k] = a[k];
    g7[5] = dist[g];
    g7[6] = sw[g];
    float r = bl2[0];
#pragma unroll
    for (int k2 = 0; k2 < 5; k2++) {
        float t = bl1[k2];
#pragma unroll
        for (int j = 0; j < 7; j++) t += g7[j] * Wl1[j * 5 + k2];
        t = fmaxf(t, 0.f);
        r += t * Wl2[k2];
    }
    out[g] = r;
}

// ---------------- launch ----------------

extern "C" void kernel_launch(void* const* d_in, const int* in_sizes, int n_in,
                              void* d_out, int out_size, void* d_ws, size_t ws_size,
                              hipStream_t stream) {
    const float* x    = (const float*)d_in[0];
    const int*   ei   = (const int*)d_in[1];
    const int*   batch= (const int*)d_in[2];
    const float* dist = (const float*)d_in[3];
    const float* sw   = (const float*)d_in[4];
    const float* W1   = (const float*)d_in[5];
    const float* b1   = (const float*)d_in[6];
    const float* W2   = (const float*)d_in[7];
    const float* b2   = (const float*)d_in[8];
    const float* W3   = (const float*)d_in[9];
    const float* b3   = (const float*)d_in[10];
    const float* Wl   = (const float*)d_in[11];
    const float* bl   = (const float*)d_in[12];
    const float* Wl1  = (const float*)d_in[13];
    const float* bl1  = (const float*)d_in[14];
    const float* Wl2  = (const float*)d_in[15];
    const float* bl2  = (const float*)d_in[16];

    int N = in_sizes[0];
    int E = in_sizes[1] / 2;
    int G = in_sizes[3];

    char* ws = (char*)d_ws;
    size_t off = 0;
    auto alloc = [&](size_t bytes) -> char* {
        char* p = ws + off;
        off += (bytes + 255) & ~(size_t)255;
        return p;
    };
    int*   cnt       = (int*)alloc((size_t)N * 4);
    int*   row_start = (int*)alloc((size_t)N * 4);
    int*   cursor    = (int*)alloc((size_t)N * 4);
    float* dinv      = (float*)alloc((size_t)N * 4);
    int*   bsum      = (int*)alloc(SCAN_B * 4);
    int*   bofs      = (int*)alloc(SCAN_B * 4);
    int2*  csr       = (int2*)alloc((size_t)E * 8);
    char*  bufA      = alloc((size_t)N * HID * 2);  // bf16 rows (128 B)
    char*  bufB      = alloc((size_t)N * HID * 2);
    float* psum      = (float*)alloc((size_t)G * HID * 4);
    int*   pcnt      = (int*)alloc((size_t)G * 4);

    hipMemsetAsync(cnt, 0, (size_t)N * 4, stream);
    hipMemsetAsync(psum, 0, (size_t)G * HID * 4, stream);
    hipMemsetAsync(pcnt, 0, (size_t)G * 4, stream);

    count_kernel<<<2048, 256, 0, stream>>>(ei, E, cnt);
    dinv_kernel<<<(N + 255) / 256, 256, 0, stream>>>(cnt, dinv, batch, pcnt, N);
    scan_sum<<<SCAN_B, SCAN_T, 0, stream>>>(cnt, N, bsum);
    scan_bsum<<<1, 64, 0, stream>>>(bsum, bofs);
    scan_chunk<<<SCAN_B, SCAN_T, 0, stream>>>(cnt, N, bofs, row_start, cursor);
    fill_part<<<2048, 256, 0, stream>>>(ei, E, N, dinv, cursor, csr);

    int nb = (N + 3) / 4;
    layer1_kernel<<<nb, 256, 0, stream>>>(x, csr, row_start, cnt, dinv, W1, b1, W2,
                                          (uint2*)bufA, N);
    p64_kernel<true, false><<<nb, 256, 0, stream>>>((const uint4*)bufA, csr, row_start, cnt,
                                                    dinv, b2, W3, (uint4*)bufB, nullptr,
                                                    nullptr, N);
    p64_kernel<false, true><<<nb, 256, 0, stream>>>((const uint4*)bufB, csr, row_start, cnt,
                                                    dinv, b3, nullptr, nullptr, psum, batch, N);
    head_kernel<<<(G + 255) / 256, 256, 0, stream>>>(psum, pcnt, dist, sw, Wl, bl, Wl1, bl1, Wl2,
                                                     bl2, (float*)d_out, G);
}

// Round 8
// 427.787 us; speedup vs baseline: 1.0958x; 1.0958x over previous
//
#include <hip/hip_runtime.h>
#include <hip/hip_bf16.h>

#define HID 64
#define WPAD 68
#define SCAN_B 128
#define SCAN_T 256
#define NXCD 8

typedef float v2f __attribute__((ext_vector_type(2)));

// bf16 rows: 64 bf16 = 128 B = 16 uint2. Lane sl in [0,16) owns uint2 sl = feats [4sl,4sl+4).
static __device__ __forceinline__ float bflo(unsigned u) { return __uint_as_float(u << 16); }
static __device__ __forceinline__ float bfhi(unsigned u) {
    return __uint_as_float(u & 0xFFFF0000u);
}
static __device__ __forceinline__ unsigned packbf(float a, float b) {
    __hip_bfloat16 ha = __float2bfloat16(a), hb = __float2bfloat16(b);
    unsigned short ua = *reinterpret_cast<unsigned short*>(&ha);
    unsigned short ub = *reinterpret_cast<unsigned short*>(&hb);
    return (unsigned)ua | ((unsigned)ub << 16);
}

// ---------------- CSR build ----------------

__global__ __launch_bounds__(256) void count_kernel(const int* __restrict__ ei, int E,
                                                    int* __restrict__ cnt) {
    int stride = gridDim.x * blockDim.x;
    for (int e = blockIdx.x * blockDim.x + threadIdx.x; e < E; e += stride)
        atomicAdd(&cnt[ei[E + e]], 1);
}

// dinv + pre-scaled x + pcnt + zero-pad rows of bufA/bufB (row N)
__global__ void dinv_kernel(const int* __restrict__ cnt, const float* __restrict__ x,
                            float* __restrict__ dinv, float* __restrict__ xs,
                            const int* __restrict__ batch, int* __restrict__ pcnt,
                            uint2* __restrict__ padA, uint2* __restrict__ padB, int N) {
    int gid = blockIdx.x * blockDim.x + threadIdx.x;
    if (gid < 16) {
        padA[gid] = make_uint2(0u, 0u);
        padB[gid] = make_uint2(0u, 0u);
    }
    int stride = gridDim.x * blockDim.x;
    for (int n = gid; n < N; n += stride) {
        float dn = rsqrtf((float)(cnt[n] + 1));  // deg includes self-loop
        dinv[n] = dn;
        xs[n] = dn * x[n];
        atomicAdd(&pcnt[batch[n]], 1);
    }
}

__global__ void scan_sum(const int* __restrict__ cnt, int N, int* __restrict__ bsum) {
    int b = blockIdx.x;
    int chunk = (N + SCAN_B - 1) / SCAN_B;
    int lo = b * chunk, hi = min(lo + chunk, N);
    int s = 0;
    for (int i = lo + threadIdx.x; i < hi; i += SCAN_T) s += cnt[i];
    for (int off = 32; off; off >>= 1) s += __shfl_xor(s, off);
    __shared__ int red[SCAN_T / 64];
    int wave = threadIdx.x >> 6, lane = threadIdx.x & 63;
    if (lane == 0) red[wave] = s;
    __syncthreads();
    if (threadIdx.x == 0) {
        int t = 0;
        for (int w = 0; w < SCAN_T / 64; w++) t += red[w];
        bsum[b] = t;
    }
}

// scan within chunk; block-level carry computed in-kernel from bsum (no scan_bsum pass)
__global__ void scan_chunk(const int* __restrict__ cnt, int N, const int* __restrict__ bsum,
                           int* __restrict__ row_start, int* __restrict__ cursor) {
    int b = blockIdx.x;
    int chunk = (N + SCAN_B - 1) / SCAN_B;
    int lo = b * chunk, hi = min(lo + chunk, N);
    __shared__ int s[SCAN_T];
    __shared__ int carry;
    {
        int v = (threadIdx.x < b) ? bsum[threadIdx.x] : 0;  // b < SCAN_B <= 256
        for (int off = 32; off; off >>= 1) v += __shfl_xor(v, off);
        __shared__ int red[SCAN_T / 64];
        int wave = threadIdx.x >> 6, lane = threadIdx.x & 63;
        if (lane == 0) red[wave] = v;
        __syncthreads();
        if (threadIdx.x == 0) {
            int t = 0;
            for (int w = 0; w < SCAN_T / 64; w++) t += red[w];
            carry = t;
        }
    }
    __syncthreads();
    for (int base = lo; base < hi; base += SCAN_T) {
        int i = base + threadIdx.x;
        int v = (i < hi) ? cnt[i] : 0;
        s[threadIdx.x] = v;
        __syncthreads();
        for (int off = 1; off < SCAN_T; off <<= 1) {
            int t = (threadIdx.x >= off) ? s[threadIdx.x - off] : 0;
            __syncthreads();
            s[threadIdx.x] += t;
            __syncthreads();
        }
        int incl = s[threadIdx.x];
        int c = carry;
        if (i < hi) {
            int ex = c + incl - v;
            row_start[i] = ex;
            cursor[i] = ex;
        }
        __syncthreads();
        if (threadIdx.x == SCAN_T - 1) carry = c + incl;
        __syncthreads();
    }
}

// index-only CSR fill, XCD-partitioned by dst range (stores stay in one local L2)
__global__ __launch_bounds__(256) void fill_part(const int* __restrict__ ei, int E, int N,
                                                 int* __restrict__ cursor,
                                                 int* __restrict__ csr) {
    int xcd = blockIdx.x & (NXCD - 1);
    int sl = blockIdx.x >> 3;
    int nsl = gridDim.x >> 3;
    int nlo = (int)((long long)N * xcd / NXCD);
    int nhi = (int)((long long)N * (xcd + 1) / NXCD);
    int stride = nsl * blockDim.x;
    for (int e = sl * blockDim.x + threadIdx.x; e < E; e += stride) {
        int d = ei[E + e];
        if (d >= nlo && d < nhi) {
            int pos = atomicAdd(&cursor[d], 1);
            csr[pos] = ei[e];
        }
    }
}

// ---------------- LDS weight staging (padded) + quarter-split matmul ----------------

__device__ __forceinline__ void stageW(const float* __restrict__ W, float* __restrict__ sW) {
    for (int i = threadIdx.x; i < HID * HID; i += 256) {
        int r = i >> 6, c = i & 63;
        sW[r * WPAD + c] = W[i];
    }
    __syncthreads();
}

__device__ __forceinline__ float4 qmatmul(float4 h4, const float* __restrict__ sW, int q, int sl) {
    float4 z4 = make_float4(0.f, 0.f, 0.f, 0.f);
#pragma unroll
    for (int t = 0; t < 16; t++) {
        int k = (q << 4) + t;
        int srclane = 20 * q + (t >> 2);
        float comp = ((t & 3) == 0) ? h4.x : ((t & 3) == 1) ? h4.y : ((t & 3) == 2) ? h4.z : h4.w;
        float hk = __shfl(comp, srclane);
        const float4 w4 = *reinterpret_cast<const float4*>(&sW[k * WPAD + sl * 4]);
        z4.x += hk * w4.x; z4.y += hk * w4.y; z4.z += hk * w4.z; z4.w += hk * w4.w;
    }
#pragma unroll
    for (int off = 16; off <= 32; off <<= 1) {
        z4.x += __shfl_xor(z4.x, off);
        z4.y += __shfl_xor(z4.y, off);
        z4.z += __shfl_xor(z4.z, off);
        z4.w += __shfl_xor(z4.w, off);
    }
    return z4;
}

// ---------------- Layer 1: scalar propagate (pre-scaled xs) + fused matmul -> bf16 z' ----

__global__ __launch_bounds__(256) void layer1_kernel(
    const float* __restrict__ xs, const int* __restrict__ csr,
    const int* __restrict__ row_start, const int* __restrict__ cnt, const float* __restrict__ dinv,
    const float* __restrict__ W1, const float* __restrict__ b1, const float* __restrict__ W2,
    uint2* __restrict__ zb, int N) {
    __shared__ float sW2[HID * WPAD];
    stageW(W2, sW2);
    int lane = threadIdx.x & 63;
    int q = lane >> 4, sl = lane & 15;
    int n = blockIdx.x * 4 + (threadIdx.x >> 6);
    if (n >= N) return;
    int start = row_start[n], deg = cnt[n];
    float acc = 0.f;
    for (int i = start + lane; i < start + deg; i += 64)
        acc += xs[csr[i]];
#pragma unroll
    for (int off = 32; off; off >>= 1) acc += __shfl_xor(acc, off);
    float dn = dinv[n];
    float p = dn * (acc + xs[n]);  // wave-uniform: dinv[d]*(sum z'[s] + z'[d])
    float h = fmaxf(p * W1[lane] + b1[lane], 0.f);  // one feature per lane
    float4 h4;
    h4.x = __shfl(h, (sl << 2) + 0);
    h4.y = __shfl(h, (sl << 2) + 1);
    h4.z = __shfl(h, (sl << 2) + 2);
    h4.w = __shfl(h, (sl << 2) + 3);
    float4 z4 = qmatmul(h4, sW2, q, sl);
    if (q == 0)  // store pre-scaled z' = dinv * z
        zb[(size_t)n * 16 + sl] =
            make_uint2(packbf(dn * z4.x, dn * z4.y), packbf(dn * z4.z, dn * z4.w));
}

// ---------------- 64-wide propagate over pre-scaled bf16 rows (layers 2,3) --------------
// Lane = (q 0..3, sl 0..15); 4 edges per gather instruction; index-only CSR (norm folded
// into rows); dead slots -> zero row N; packed f32 adds.
// FUSE: out' = dinv * (relu(P+bias) @ W) -> bf16   (layer 2)
// POOL: segmented LDS reduce + one fp32 atomic run per distinct graph (layer 3 + pool)

template <bool FUSE, bool POOL>
__global__ __launch_bounds__(256) void p64_kernel(
    const uint2* __restrict__ zb, const int* __restrict__ csr,
    const int* __restrict__ row_start, const int* __restrict__ cnt, const float* __restrict__ dinv,
    const float* __restrict__ bias, const float* __restrict__ W,
    uint2* __restrict__ outb, float* __restrict__ outp, const int* __restrict__ batch, int N) {
    __shared__ float sW[FUSE ? HID * WPAD : 1];
    __shared__ float pbuf[POOL ? 4 : 1][POOL ? HID : 1];
    __shared__ int pg[4];
    if (FUSE) stageW(W, sW);
    int lane = threadIdx.x & 63;
    int wid = threadIdx.x >> 6;
    int q = lane >> 4, sl = lane & 15;
    int n = blockIdx.x * 4 + wid;
    bool valid = n < N;
    if (!POOL && !valid) return;
    int nc = valid ? n : 0;
    int start = row_start[nc];
    int deg = valid ? cnt[nc] : 0;
    float dn = dinv[nc];

    v2f a0 = {0.f, 0.f}, a1 = {0.f, 0.f};
    for (int base = 0; base < deg; base += 64) {
        int m = deg - base; if (m > 64) m = 64;
        int ew = (lane < m) ? csr[start + base + lane] : N;  // pad -> zero row
        int mt = (m + 3) >> 2;
        for (int tb = 0; tb < mt; tb += 4) {
#pragma unroll
            for (int u = 0; u < 4; u++) {
                int t = tb + u;
                int eidx = ((t << 2) + q) & 63;
                int ss = __shfl(ew, eidx);
                ss = (t < mt) ? ss : N;  // wave-uniform predicate -> zero row
                const uint2 r = zb[(size_t)ss * 16 + sl];
                v2f u0 = {bflo(r.x), bfhi(r.x)};
                v2f u1 = {bflo(r.y), bfhi(r.y)};
                a0 += u0;
                a1 += u1;
            }
        }
    }
    float4 acc = make_float4(a0.x, a0.y, a1.x, a1.y);
#pragma unroll
    for (int off = 16; off <= 32; off <<= 1) {
        acc.x += __shfl_xor(acc.x, off);
        acc.y += __shfl_xor(acc.y, off);
        acc.z += __shfl_xor(acc.z, off);
        acc.w += __shfl_xor(acc.w, off);
    }
    // self term (pre-scaled) + dinv[d] scale
    {
        uint2 su = zb[(size_t)nc * 16 + sl];
        acc.x = dn * (acc.x + bflo(su.x));
        acc.y = dn * (acc.y + bfhi(su.x));
        acc.z = dn * (acc.z + bflo(su.y));
        acc.w = dn * (acc.w + bfhi(su.y));
    }
    const float4 b4 = *reinterpret_cast<const float4*>(&bias[sl << 2]);

    if (FUSE) {
        float4 h4;
        h4.x = fmaxf(acc.x + b4.x, 0.f);
        h4.y = fmaxf(acc.y + b4.y, 0.f);
        h4.z = fmaxf(acc.z + b4.z, 0.f);
        h4.w = fmaxf(acc.w + b4.w, 0.f);
        float4 z4 = qmatmul(h4, sW, q, sl);
        if (q == 0)  // store pre-scaled for next propagate
            outb[(size_t)n * 16 + sl] =
                make_uint2(packbf(dn * z4.x, dn * z4.y), packbf(dn * z4.z, dn * z4.w));
    } else if (POOL) {
        acc.x += b4.x; acc.y += b4.y; acc.z += b4.z; acc.w += b4.w;
        if (q == 0) {
            *reinterpret_cast<float4*>(&pbuf[wid][sl << 2]) = acc;
            if (sl == 0) pg[wid] = valid ? batch[n] : -1;
        }
        __syncthreads();
        if (wid == 0) {
            int j = lane;
            float v = 0.f;
            int gp = -1;
#pragma unroll
            for (int w = 0; w < 4; w++) {
                int gw = pg[w];  // wave-uniform
                if (gw < 0) continue;
                if (gw == gp) {
                    v += pbuf[w][j];
                } else {
                    if (gp >= 0) atomicAdd(&outp[(size_t)gp * HID + j], v);
                    v = pbuf[w][j];
                    gp = gw;
                }
            }
            if (gp >= 0) atomicAdd(&outp[(size_t)gp * HID + j], v);
        }
    }
}

// ---------------- head ----------------

__global__ void head_kernel(const float* __restrict__ psum, const int* __restrict__ pcnt,
                            const float* __restrict__ dist, const float* __restrict__ sw,
                            const float* __restrict__ Wl, const float* __restrict__ bl,
                            const float* __restrict__ Wl1, const float* __restrict__ bl1,
                            const float* __restrict__ Wl2, const float* __restrict__ bl2,
                            float* __restrict__ out, int G) {
    int g = blockIdx.x * blockDim.x + threadIdx.x;
    if (g >= G) return;
    float invc = 1.f / fmaxf((float)pcnt[g], 1.f);
    float a[5];
#pragma unroll
    for (int k = 0; k < 5; k++) a[k] = bl[k];
    for (int j = 0; j < HID; j++) {
        float p = psum[(size_t)g * HID + j] * invc;
#pragma unroll
        for (int k = 0; k < 5; k++) a[k] += p * Wl[j * 5 + k];
    }
    float g7[7];
#pragma unroll
    for (int k = 0; k < 5; k++) g7[k] = a[k];
    g7[5] = dist[g];
    g7[6] = sw[g];
    float r = bl2[0];
#pragma unroll
    for (int k2 = 0; k2 < 5; k2++) {
        float t = bl1[k2];
#pragma unroll
        for (int j = 0; j < 7; j++) t += g7[j] * Wl1[j * 5 + k2];
        t = fmaxf(t, 0.f);
        r += t * Wl2[k2];
    }
    out[g] = r;
}

// ---------------- launch ----------------

extern "C" void kernel_launch(void* const* d_in, const int* in_sizes, int n_in,
                              void* d_out, int out_size, void* d_ws, size_t ws_size,
                              hipStream_t stream) {
    const float* x    = (const float*)d_in[0];
    const int*   ei   = (const int*)d_in[1];
    const int*   batch= (const int*)d_in[2];
    const float* dist = (const float*)d_in[3];
    const float* sw   = (const float*)d_in[4];
    const float* W1   = (const float*)d_in[5];
    const float* b1   = (const float*)d_in[6];
    const float* W2   = (const float*)d_in[7];
    const float* b2   = (const float*)d_in[8];
    const float* W3   = (const float*)d_in[9];
    const float* b3   = (const float*)d_in[10];
    const float* Wl   = (const float*)d_in[11];
    const float* bl   = (const float*)d_in[12];
    const float* Wl1  = (const float*)d_in[13];
    const float* bl1  = (const float*)d_in[14];
    const float* Wl2  = (const float*)d_in[15];
    const float* bl2  = (const float*)d_in[16];

    int N = in_sizes[0];
    int E = in_sizes[1] / 2;
    int G = in_sizes[3];

    char* ws = (char*)d_ws;
    size_t off = 0;
    auto alloc = [&](size_t bytes) -> char* {
        char* p = ws + off;
        off += (bytes + 255) & ~(size_t)255;
        return p;
    };
    // contiguous zero-init region: cnt | psum | pcnt
    char*  zreg      = ws;
    int*   cnt       = (int*)alloc((size_t)N * 4);
    float* psum      = (float*)alloc((size_t)G * HID * 4);
    int*   pcnt      = (int*)alloc((size_t)G * 4);
    size_t zbytes    = off;
    int*   row_start = (int*)alloc((size_t)N * 4);
    int*   cursor    = (int*)alloc((size_t)N * 4);
    float* dinv      = (float*)alloc((size_t)N * 4);
    float* xs        = (float*)alloc((size_t)N * 4);
    int*   bsum      = (int*)alloc(SCAN_B * 4);
    int*   csr       = (int*)alloc((size_t)E * 4);
    char*  bufA      = alloc(((size_t)N + 1) * HID * 2);  // bf16 rows + zero pad row N
    char*  bufB      = alloc(((size_t)N + 1) * HID * 2);

    hipMemsetAsync(zreg, 0, zbytes, stream);

    count_kernel<<<2048, 256, 0, stream>>>(ei, E, cnt);
    dinv_kernel<<<(N + 255) / 256, 256, 0, stream>>>(
        cnt, x, dinv, xs, batch, pcnt,
        (uint2*)(bufA + (size_t)N * HID * 2), (uint2*)(bufB + (size_t)N * HID * 2), N);
    scan_sum<<<SCAN_B, SCAN_T, 0, stream>>>(cnt, N, bsum);
    scan_chunk<<<SCAN_B, SCAN_T, 0, stream>>>(cnt, N, bsum, row_start, cursor);
    fill_part<<<2048, 256, 0, stream>>>(ei, E, N, cursor, csr);

    int nb = (N + 3) / 4;
    layer1_kernel<<<nb, 256, 0, stream>>>(xs, csr, row_start, cnt, dinv, W1, b1, W2,
                                          (uint2*)bufA, N);
    p64_kernel<true, false><<<nb, 256, 0, stream>>>((const uint2*)bufA, csr, row_start, cnt,
                                                    dinv, b2, W3, (uint2*)bufB, nullptr,
                                                    nullptr, N);
    p64_kernel<false, true><<<nb, 256, 0, stream>>>((const uint2*)bufB, csr, row_start, cnt,
                                                    dinv, b3, nullptr, nullptr, psum, batch, N);
    head_kernel<<<(G + 255) / 256, 256, 0, stream>>>(psum, pcnt, dist, sw, Wl, bl, Wl1, bl1, Wl2,
                                                     bl2, (float*)d_out, G);
}